// Round 1
// baseline (145.821 us; speedup 1.0000x reference)
//
#include <hip/hip_runtime.h>
#include <hip/hip_bf16.h>

#define Bdim 256
#define Sdim 196
#define Hdim 1024
#define Fdim 2048
#define BH (Bdim*Hdim)      // 262144
#define BS (Bdim*Sdim)      // 50176

// ---------------- fast tanh: 1 - 2/(e^{2x}+1), exp via v_exp_f32 ----------------
__device__ __forceinline__ float tanh_fast(float x) {
    float e = __expf(2.0f * x);                      // e^{2x}
    return 1.0f - 2.0f * __builtin_amdgcn_rcpf(e + 1.0f);
}

// ---------------- Kernel A: q partials = ha@W_ha^T + hf@W_hf^T (K-split) --------
// virtual K = 2048 (first 1024 -> ha/W_ha, second 1024 -> hf/W_hf)
// tile: TM=64 (b) x TN=128 (h), TK=32; 256 threads, micro 4x8
#define TM 64
#define TN 128
#define TK 32

__global__ __launch_bounds__(256) void gemm_q_part(
    const float* __restrict__ ha, const float* __restrict__ hf,
    const float* __restrict__ Wha, const float* __restrict__ Whf,
    float* __restrict__ qpart, int kchunk)
{
    __shared__ float As[TK][TM + 4];   // [k][b], pad 68 -> 16B-aligned rows
    __shared__ float Ws[TK][TN + 4];   // [k][h], pad 132 -> 16B-aligned rows

    const int tid = threadIdx.x;
    const int th  = tid & 15;          // h-group: 16 groups * 8 = 128
    const int tb  = tid >> 4;          // b-group: 16 groups * 4 = 64
    const int h0  = blockIdx.x * TN;
    const int b0  = blockIdx.y * TM;
    const int z   = blockIdx.z;
    const int kv_base = z * kchunk;

    float acc[4][8];
    #pragma unroll
    for (int i = 0; i < 4; ++i)
        #pragma unroll
        for (int j = 0; j < 8; ++j) acc[i][j] = 0.0f;

    float4 xv[2], wv[4];

    auto load_regs = [&](int t) {
        int kv = kv_base + t * TK;
        const float* X; const float* W; int k0;
        if (kv < 1024) { X = ha; W = Wha; k0 = kv; }
        else           { X = hf; W = Whf; k0 = kv - 1024; }
        #pragma unroll
        for (int r = 0; r < 2; ++r) {
            int idx = tid + r * 256;
            int row = idx >> 3, kq = idx & 7;
            xv[r] = *reinterpret_cast<const float4*>(X + (size_t)(b0 + row) * Hdim + k0 + kq * 4);
        }
        #pragma unroll
        for (int r = 0; r < 4; ++r) {
            int idx = tid + r * 256;
            int row = idx >> 3, kq = idx & 7;
            wv[r] = *reinterpret_cast<const float4*>(W + (size_t)(h0 + row) * Hdim + k0 + kq * 4);
        }
    };

    const int ntiles = kchunk / TK;
    load_regs(0);

    for (int t = 0; t < ntiles; ++t) {
        // regs -> LDS (transposed)
        #pragma unroll
        for (int r = 0; r < 2; ++r) {
            int idx = tid + r * 256;
            int row = idx >> 3, kq = idx & 7;
            As[kq * 4 + 0][row] = xv[r].x;
            As[kq * 4 + 1][row] = xv[r].y;
            As[kq * 4 + 2][row] = xv[r].z;
            As[kq * 4 + 3][row] = xv[r].w;
        }
        #pragma unroll
        for (int r = 0; r < 4; ++r) {
            int idx = tid + r * 256;
            int row = idx >> 3, kq = idx & 7;
            Ws[kq * 4 + 0][row] = wv[r].x;
            Ws[kq * 4 + 1][row] = wv[r].y;
            Ws[kq * 4 + 2][row] = wv[r].z;
            Ws[kq * 4 + 3][row] = wv[r].w;
        }
        __syncthreads();

        if (t + 1 < ntiles) load_regs(t + 1);   // prefetch next tile into regs

        #pragma unroll
        for (int k = 0; k < TK; ++k) {
            float4 a0 = *reinterpret_cast<const float4*>(&As[k][tb * 4]);
            float4 w0 = *reinterpret_cast<const float4*>(&Ws[k][th * 8]);
            float4 w1 = *reinterpret_cast<const float4*>(&Ws[k][th * 8 + 4]);
            float a[4] = {a0.x, a0.y, a0.z, a0.w};
            float w[8] = {w0.x, w0.y, w0.z, w0.w, w1.x, w1.y, w1.z, w1.w};
            #pragma unroll
            for (int i = 0; i < 4; ++i)
                #pragma unroll
                for (int j = 0; j < 8; ++j)
                    acc[i][j] += a[i] * w[j];
        }
        __syncthreads();
    }

    // write partials
    #pragma unroll
    for (int i = 0; i < 4; ++i) {
        int b = b0 + tb * 4 + i;
        float* dst = qpart + (size_t)z * BH + (size_t)b * Hdim + h0 + th * 8;
        float4 o0 = {acc[i][0], acc[i][1], acc[i][2], acc[i][3]};
        float4 o1 = {acc[i][4], acc[i][5], acc[i][6], acc[i][7]};
        *reinterpret_cast<float4*>(dst)     = o0;
        *reinterpret_cast<float4*>(dst + 4) = o1;
    }
}

// ---------------- Kernel A2: reduce partials + biases -> q ----------------------
__global__ __launch_bounds__(256) void reduce_q(
    const float* __restrict__ qpart, const float* __restrict__ b_ha,
    const float* __restrict__ b_hf, float* __restrict__ q, int ks)
{
    int idx = blockIdx.x * 256 + threadIdx.x;       // float4 index over BH/4
    size_t off = (size_t)idx * 4;
    int h = (int)(off & (Hdim - 1));
    float4 s = {0.f, 0.f, 0.f, 0.f};
    for (int z = 0; z < ks; ++z) {
        float4 v = *reinterpret_cast<const float4*>(qpart + (size_t)z * BH + off);
        s.x += v.x; s.y += v.y; s.z += v.z; s.w += v.w;
    }
    float4 ba = *reinterpret_cast<const float4*>(b_ha + h);
    float4 bb = *reinterpret_cast<const float4*>(b_hf + h);
    s.x += ba.x + bb.x; s.y += ba.y + bb.y; s.z += ba.z + bb.z; s.w += ba.w + bb.w;
    *reinterpret_cast<float4*>(q + off) = s;
}

// ---------------- Kernel B: scores[b,s] = sum_h tanh(q+p)*w_alpha + b_alpha -----
// one wave per (b,s) row; block = 4 waves handles 16 s-values; q,w_alpha in LDS
__global__ __launch_bounds__(256) void scores_kernel(
    const float* __restrict__ q, const float* __restrict__ p_att,
    const float* __restrict__ w_alpha, const float* __restrict__ b_alpha,
    float* __restrict__ scores)
{
    __shared__ float qs[Hdim];
    __shared__ float wa[Hdim];
    const int b = blockIdx.y;
    const int tid = threadIdx.x;

    *reinterpret_cast<float4*>(qs + tid * 4) =
        *reinterpret_cast<const float4*>(q + (size_t)b * Hdim + tid * 4);
    *reinterpret_cast<float4*>(wa + tid * 4) =
        *reinterpret_cast<const float4*>(w_alpha + tid * 4);
    __syncthreads();

    const int wave = tid >> 6, lane = tid & 63;
    const float balpha = b_alpha[0];

    #pragma unroll
    for (int it = 0; it < 4; ++it) {
        int s = blockIdx.x * 16 + wave * 4 + it;
        if (s < Sdim) {
            const float* p = p_att + ((size_t)b * Sdim + s) * Hdim;
            float acc = 0.0f;
            #pragma unroll
            for (int i = 0; i < 4; ++i) {
                int i4 = i * 64 + lane;                     // float4 index 0..255
                float4 pv = *reinterpret_cast<const float4*>(p + i4 * 4);
                float4 qv = *reinterpret_cast<const float4*>(qs + i4 * 4);
                float4 wv = *reinterpret_cast<const float4*>(wa + i4 * 4);
                acc += tanh_fast(pv.x + qv.x) * wv.x;
                acc += tanh_fast(pv.y + qv.y) * wv.y;
                acc += tanh_fast(pv.z + qv.z) * wv.z;
                acc += tanh_fast(pv.w + qv.w) * wv.w;
            }
            #pragma unroll
            for (int m = 32; m >= 1; m >>= 1) acc += __shfl_xor(acc, m, 64);
            if (lane == 0) scores[(size_t)b * Sdim + s] = acc + balpha;
        }
    }
}

// ---------------- Kernel C: softmax over s per b --------------------------------
__global__ __launch_bounds__(256) void softmax_kernel(
    const float* __restrict__ scores, float* __restrict__ weight)
{
    __shared__ float red[4];
    const int b = blockIdx.x, tid = threadIdx.x;
    float v = (tid < Sdim) ? scores[(size_t)b * Sdim + tid] : -1e30f;
    float m = v;
    #pragma unroll
    for (int mk = 32; mk >= 1; mk >>= 1) m = fmaxf(m, __shfl_xor(m, mk, 64));
    if ((tid & 63) == 0) red[tid >> 6] = m;
    __syncthreads();
    m = fmaxf(fmaxf(red[0], red[1]), fmaxf(red[2], red[3]));

    float e = (tid < Sdim) ? __expf(v - m) : 0.0f;
    float ssum = e;
    #pragma unroll
    for (int mk = 32; mk >= 1; mk >>= 1) ssum += __shfl_xor(ssum, mk, 64);
    __syncthreads();
    if ((tid & 63) == 0) red[tid >> 6] = ssum;
    __syncthreads();
    float tot = red[0] + red[1] + red[2] + red[3];
    if (tid < Sdim) weight[(size_t)b * Sdim + tid] = e * __builtin_amdgcn_rcpf(tot);
}

// ---------------- Kernel D: att_res[b,f] = sum_s weight[b,s]*att_feats[b,s,f] ---
// block = (f-tile of 512, b); 256 threads x float2; weights staged in LDS
__global__ __launch_bounds__(256) void attres_kernel(
    const float* __restrict__ weight, const float* __restrict__ att_feats,
    float* __restrict__ out)
{
    __shared__ float wl[Sdim];
    const int b = blockIdx.y;
    const int tid = threadIdx.x;
    if (tid < Sdim) wl[tid] = weight[(size_t)b * Sdim + tid];
    __syncthreads();

    const int f = blockIdx.x * 512 + tid * 2;
    const float* base = att_feats + (size_t)b * Sdim * Fdim + f;
    float2 acc = {0.0f, 0.0f};
    #pragma unroll 4
    for (int s = 0; s < Sdim; ++s) {
        float2 v = *reinterpret_cast<const float2*>(base + (size_t)s * Fdim);
        float w = wl[s];
        acc.x += w * v.x;
        acc.y += w * v.y;
    }
    *reinterpret_cast<float2*>(out + (size_t)b * Fdim + f) = acc;
}

// ---------------- launch --------------------------------------------------------
extern "C" void kernel_launch(void* const* d_in, const int* in_sizes, int n_in,
                              void* d_out, int out_size, void* d_ws, size_t ws_size,
                              hipStream_t stream) {
    const float* ha       = (const float*)d_in[0];
    const float* hf       = (const float*)d_in[1];
    const float* att_f    = (const float*)d_in[2];
    const float* p_att    = (const float*)d_in[3];
    const float* W_ha     = (const float*)d_in[4];
    const float* b_ha     = (const float*)d_in[5];
    const float* W_hf     = (const float*)d_in[6];
    const float* b_hf     = (const float*)d_in[7];
    const float* w_alpha  = (const float*)d_in[8];
    const float* b_alpha  = (const float*)d_in[9];
    float* out = (float*)d_out;
    float* ws  = (float*)d_ws;

    // pick K-split so workspace fits: KS*BH + BH + 2*BS floats
    int KS = 16;
    while (KS > 1 && ((size_t)KS * BH + BH + 2 * BS) * sizeof(float) > ws_size) KS >>= 1;

    float* qpart  = ws;
    float* q      = ws + (size_t)KS * BH;
    float* scores = q + BH;
    float* weight = scores + BS;

    dim3 gA(Hdim / TN, Bdim / TM, KS);
    gemm_q_part<<<gA, 256, 0, stream>>>(ha, hf, W_ha, W_hf, qpart, 2048 / KS);

    reduce_q<<<dim3(BH / 1024), 256, 0, stream>>>(qpart, b_ha, b_hf, q, KS);

    dim3 gB((Sdim + 15) / 16, Bdim);
    scores_kernel<<<gB, 256, 0, stream>>>(q, p_att, w_alpha, b_alpha, scores);

    softmax_kernel<<<dim3(Bdim), 256, 0, stream>>>(scores, weight);

    dim3 gD(Fdim / 512, Bdim);
    attres_kernel<<<gD, 256, 0, stream>>>(weight, att_f, out);
}

// Round 2
// 136.927 us; speedup vs baseline: 1.0650x; 1.0650x over previous
//
#include <hip/hip_runtime.h>
#include <hip/hip_bf16.h>

#define Bdim 256
#define Sdim 196
#define Hdim 1024
#define Fdim 2048
#define BH (Bdim*Hdim)      // 262144

// ---------------- fast tanh: 1 - 2/(e^{2x}+1), exp via v_exp_f32 ----------------
__device__ __forceinline__ float tanh_fast(float x) {
    float e = __expf(2.0f * x);                      // e^{2x}
    return 1.0f - 2.0f * __builtin_amdgcn_rcpf(e + 1.0f);
}

// ---------------- Kernel A: q partials = ha@W_ha^T + hf@W_hf^T (K-split) --------
// virtual K = 2048 (first 1024 -> ha/W_ha, second 1024 -> hf/W_hf)
// tile: TM=64 (b) x TN=128 (h), TK=32; 256 threads, micro 4x8
#define TM 64
#define TN 128
#define TK 32

__global__ __launch_bounds__(256) void gemm_q_part(
    const float* __restrict__ ha, const float* __restrict__ hf,
    const float* __restrict__ Wha, const float* __restrict__ Whf,
    float* __restrict__ qpart, int kchunk)
{
    __shared__ float As[TK][TM + 4];
    __shared__ float Ws[TK][TN + 4];

    const int tid = threadIdx.x;
    const int th  = tid & 15;          // h-group: 16 groups * 8 = 128
    const int tb  = tid >> 4;          // b-group: 16 groups * 4 = 64
    const int h0  = blockIdx.x * TN;
    const int b0  = blockIdx.y * TM;
    const int z   = blockIdx.z;
    const int kv_base = z * kchunk;

    float acc[4][8];
    #pragma unroll
    for (int i = 0; i < 4; ++i)
        #pragma unroll
        for (int j = 0; j < 8; ++j) acc[i][j] = 0.0f;

    float4 xv[2], wv[4];

    auto load_regs = [&](int t) {
        int kv = kv_base + t * TK;
        const float* X; const float* W; int k0;
        if (kv < 1024) { X = ha; W = Wha; k0 = kv; }
        else           { X = hf; W = Whf; k0 = kv - 1024; }
        #pragma unroll
        for (int r = 0; r < 2; ++r) {
            int idx = tid + r * 256;
            int row = idx >> 3, kq = idx & 7;
            xv[r] = *reinterpret_cast<const float4*>(X + (size_t)(b0 + row) * Hdim + k0 + kq * 4);
        }
        #pragma unroll
        for (int r = 0; r < 4; ++r) {
            int idx = tid + r * 256;
            int row = idx >> 3, kq = idx & 7;
            wv[r] = *reinterpret_cast<const float4*>(W + (size_t)(h0 + row) * Hdim + k0 + kq * 4);
        }
    };

    const int ntiles = kchunk / TK;
    load_regs(0);

    for (int t = 0; t < ntiles; ++t) {
        #pragma unroll
        for (int r = 0; r < 2; ++r) {
            int idx = tid + r * 256;
            int row = idx >> 3, kq = idx & 7;
            As[kq * 4 + 0][row] = xv[r].x;
            As[kq * 4 + 1][row] = xv[r].y;
            As[kq * 4 + 2][row] = xv[r].z;
            As[kq * 4 + 3][row] = xv[r].w;
        }
        #pragma unroll
        for (int r = 0; r < 4; ++r) {
            int idx = tid + r * 256;
            int row = idx >> 3, kq = idx & 7;
            Ws[kq * 4 + 0][row] = wv[r].x;
            Ws[kq * 4 + 1][row] = wv[r].y;
            Ws[kq * 4 + 2][row] = wv[r].z;
            Ws[kq * 4 + 3][row] = wv[r].w;
        }
        __syncthreads();

        if (t + 1 < ntiles) load_regs(t + 1);

        #pragma unroll
        for (int k = 0; k < TK; ++k) {
            float4 a0 = *reinterpret_cast<const float4*>(&As[k][tb * 4]);
            float4 w0 = *reinterpret_cast<const float4*>(&Ws[k][th * 8]);
            float4 w1 = *reinterpret_cast<const float4*>(&Ws[k][th * 8 + 4]);
            float a[4] = {a0.x, a0.y, a0.z, a0.w};
            float w[8] = {w0.x, w0.y, w0.z, w0.w, w1.x, w1.y, w1.z, w1.w};
            #pragma unroll
            for (int i = 0; i < 4; ++i)
                #pragma unroll
                for (int j = 0; j < 8; ++j)
                    acc[i][j] += a[i] * w[j];
        }
        __syncthreads();
    }

    #pragma unroll
    for (int i = 0; i < 4; ++i) {
        int b = b0 + tb * 4 + i;
        float* dst = qpart + (size_t)z * BH + (size_t)b * Hdim + h0 + th * 8;
        float4 o0 = {acc[i][0], acc[i][1], acc[i][2], acc[i][3]};
        float4 o1 = {acc[i][4], acc[i][5], acc[i][6], acc[i][7]};
        *reinterpret_cast<float4*>(dst)     = o0;
        *reinterpret_cast<float4*>(dst + 4) = o1;
    }
}

// ---------------- Fused: reduce-q + scores + softmax + att_res ------------------
// one block per batch row b; 1024 threads = 16 waves; block stays on one CU and
// streams p_att row-block (784 KB) then att_feats row-block (1.57 MB).
__global__ __launch_bounds__(1024) void fused_kernel(
    const float* __restrict__ qpart, const float* __restrict__ b_ha,
    const float* __restrict__ b_hf,  const float* __restrict__ p_att,
    const float* __restrict__ w_alpha, const float* __restrict__ b_alpha,
    const float* __restrict__ att_feats, float* __restrict__ out, int ks)
{
    __shared__ float qs[Hdim];       // q row (after K-split reduce + biases)
    __shared__ float wa[Hdim];       // w_alpha
    __shared__ float sc[Sdim];       // scores -> weights
    __shared__ float part[Fdim];     // attres partial (upper s-half)

    const int b   = blockIdx.x;
    const int tid = threadIdx.x;

    // ---- phase 0: reduce qpart slices + biases into qs; stage w_alpha ----
    if (tid < 256) {
        size_t off = (size_t)b * Hdim + tid * 4;
        float4 s = {0.f, 0.f, 0.f, 0.f};
        for (int z = 0; z < ks; ++z) {
            float4 v = *reinterpret_cast<const float4*>(qpart + (size_t)z * BH + off);
            s.x += v.x; s.y += v.y; s.z += v.z; s.w += v.w;
        }
        float4 ba = *reinterpret_cast<const float4*>(b_ha + tid * 4);
        float4 bb = *reinterpret_cast<const float4*>(b_hf + tid * 4);
        s.x += ba.x + bb.x; s.y += ba.y + bb.y;
        s.z += ba.z + bb.z; s.w += ba.w + bb.w;
        *reinterpret_cast<float4*>(qs + tid * 4) = s;
        *reinterpret_cast<float4*>(wa + tid * 4) =
            *reinterpret_cast<const float4*>(w_alpha + tid * 4);
    }
    __syncthreads();

    // ---- phase 1: scores[s] = sum_h tanh(qs+p)*wa + b_alpha (wave per row) ----
    const int wave = tid >> 6, lane = tid & 63;
    const float balpha = b_alpha[0];
    for (int s = wave; s < Sdim; s += 16) {
        const float* p = p_att + ((size_t)b * Sdim + s) * Hdim;
        float acc = 0.0f;
        #pragma unroll
        for (int i = 0; i < 4; ++i) {
            int i4 = i * 64 + lane;
            float4 pv = *reinterpret_cast<const float4*>(p + i4 * 4);
            float4 qv = *reinterpret_cast<const float4*>(qs + i4 * 4);
            float4 wv = *reinterpret_cast<const float4*>(wa + i4 * 4);
            acc += tanh_fast(pv.x + qv.x) * wv.x;
            acc += tanh_fast(pv.y + qv.y) * wv.y;
            acc += tanh_fast(pv.z + qv.z) * wv.z;
            acc += tanh_fast(pv.w + qv.w) * wv.w;
        }
        #pragma unroll
        for (int m = 32; m >= 1; m >>= 1) acc += __shfl_xor(acc, m, 64);
        if (lane == 0) sc[s] = acc + balpha;
    }
    __syncthreads();

    // ---- phase 2: softmax over sc[0..195] (wave 0; 196 = 3*64 + 4) ----
    if (wave == 0) {
        float v0 = sc[lane];
        float v1 = sc[lane + 64];
        float v2 = sc[lane + 128];
        float v3 = (lane < Sdim - 192) ? sc[lane + 192] : -1e30f;
        float m = fmaxf(fmaxf(v0, v1), fmaxf(v2, v3));
        #pragma unroll
        for (int mk = 32; mk >= 1; mk >>= 1) m = fmaxf(m, __shfl_xor(m, mk, 64));
        float e0 = __expf(v0 - m), e1 = __expf(v1 - m), e2 = __expf(v2 - m);
        float e3 = (lane < Sdim - 192) ? __expf(v3 - m) : 0.0f;
        float ss = e0 + e1 + e2 + e3;
        #pragma unroll
        for (int mk = 32; mk >= 1; mk >>= 1) ss += __shfl_xor(ss, mk, 64);
        float r = __builtin_amdgcn_rcpf(ss);
        sc[lane]       = e0 * r;
        sc[lane + 64]  = e1 * r;
        sc[lane + 128] = e2 * r;
        if (lane < Sdim - 192) sc[lane + 192] = e3 * r;
    }
    __syncthreads();

    // ---- phase 3: att_res[f] = sum_s w[s]*att_feats[s,f]; float4/lane, s-split ----
    const int half = tid >> 9;           // 0: s in [0,98)  1: s in [98,196)
    const int fi   = (tid & 511) * 4;
    const float* base = att_feats + (size_t)b * Sdim * Fdim + fi;
    float4 a4 = {0.f, 0.f, 0.f, 0.f};
    const int s0 = half * 98, s1 = s0 + 98;
    #pragma unroll 2
    for (int s = s0; s < s1; ++s) {
        float4 v = *reinterpret_cast<const float4*>(base + (size_t)s * Fdim);
        float w = sc[s];
        a4.x += w * v.x; a4.y += w * v.y; a4.z += w * v.z; a4.w += w * v.w;
    }
    if (half) {
        *reinterpret_cast<float4*>(part + fi) = a4;
    }
    __syncthreads();
    if (!half) {
        float4 p4 = *reinterpret_cast<const float4*>(part + fi);
        a4.x += p4.x; a4.y += p4.y; a4.z += p4.z; a4.w += p4.w;
        *reinterpret_cast<float4*>(out + (size_t)b * Fdim + fi) = a4;
    }
}

// ---------------- launch --------------------------------------------------------
extern "C" void kernel_launch(void* const* d_in, const int* in_sizes, int n_in,
                              void* d_out, int out_size, void* d_ws, size_t ws_size,
                              hipStream_t stream) {
    const float* ha       = (const float*)d_in[0];
    const float* hf       = (const float*)d_in[1];
    const float* att_f    = (const float*)d_in[2];
    const float* p_att    = (const float*)d_in[3];
    const float* W_ha     = (const float*)d_in[4];
    const float* b_ha     = (const float*)d_in[5];
    const float* W_hf     = (const float*)d_in[6];
    const float* b_hf     = (const float*)d_in[7];
    const float* w_alpha  = (const float*)d_in[8];
    const float* b_alpha  = (const float*)d_in[9];
    float* out = (float*)d_out;
    float* ws  = (float*)d_ws;

    // pick K-split so workspace fits: KS*BH floats
    int KS = 16;
    while (KS > 1 && ((size_t)KS * BH) * sizeof(float) > ws_size) KS >>= 1;

    float* qpart = ws;

    dim3 gA(Hdim / TN, Bdim / TM, KS);
    gemm_q_part<<<gA, 256, 0, stream>>>(ha, hf, W_ha, W_hf, qpart, 2048 / KS);

    fused_kernel<<<dim3(Bdim), 1024, 0, stream>>>(
        qpart, b_ha, b_hf, p_att, w_alpha, b_alpha, att_f, out, KS);
}